// Round 1
// baseline (87.504 us; speedup 1.0000x reference)
//
#include <hip/hip_runtime.h>
#include <math.h>

#define NB 8192
#define NF 512
#define NP 64
#define NC 100
#define NR 16
#define EPSF 1e-4f
#define LOG2E  1.44269504088896340736f

using short8  = __attribute__((ext_vector_type(8))) short;
using floatx4 = __attribute__((ext_vector_type(4))) float;

// pack 2 f32 -> bf16 pair in one dword (truncation); validated R6-R10
__device__ __forceinline__ unsigned pk2(float a, float b) {
  return (__float_as_uint(b) & 0xffff0000u) | (__float_as_uint(a) >> 16);
}
__device__ __forceinline__ uint2 pkbf(float4 v) {
  uint2 r; r.x = pk2(v.x, v.y); r.y = pk2(v.z, v.w); return r;
}
__device__ __forceinline__ float rlane(float v, int l) {
  return __uint_as_float(__builtin_amdgcn_readlane(__float_as_uint(v), l));
}

// ---- LDS layout (bytes) ----
// staging xh[16][136]s / wh[64][136]s [0,21760) unions u_l bf16[64][128] [0,16384)
// pk4 expanded to 4 slices per wave (one per row) so the 4 rows' scans can
// be interleaved instead of serialized (R11 change).
#define OFF_XH    0
#define OFF_WH    4352
#define OFF_U     0
#define OFF_SI    21760
#define OFF_PK4   25856
#define OFF_REDB  42240
#define OFF_RMAX  43264
#define OFF_UMAX  43520
#define OFF_XSQL  43776
#define OFF_WSQL  43840
#define OFF_KGAM  44096
#define OFF_ALPH  44352
#define SMEM_SZ   44608

// One fused kernel, 512 blocks (2/CU) x 256 threads, 16 rows/block.
// GEMM (R8/R10-validated): bf16 MFMA 16x16x32, BK=128, register prefetch,
//   stride-136 staging (conflict-free b128 frag reads).
// Scan (suffix-product form, R7-validated):
//   (T,S) over a contiguous p-segment compose associatively:
//   (T,S)_{A∪B} = (T_A·T_B, S_A·T_B + S_B)  [A = lower p's].
//   One WAVE per row-group of 4: half-wave A handles p 0..31, B handles
//   p 32..63 (each descending), 4 classes/lane; cross-half combine via
//   shfl_xor 32. u (bf16) preloaded ONCE per wave into 64 VGPRs, shared
//   by all 4 rows.
//   R11: all 4 rows INTERLEAVED (own pk4 slice each) -> 4 independent
//   dependency chains through KS / main loop / combine / reduce; u-unpack
//   amortized over 4 rows. pk4 remains wave-private: ds_write -> ds_read
//   same wave, lgkmcnt-ordered (barrier-free pattern validated R9/R10).
// All reductions butterflies/fixed-order => bitwise deterministic.
__global__ __launch_bounds__(256, 2)
void ds_one(const float* __restrict__ x, const float* __restrict__ w,
            const float* __restrict__ xi, const float* __restrict__ eta,
            const float* __restrict__ beta, float* __restrict__ out)
{
  __shared__ __align__(16) char smem[SMEM_SZ];
  short*          xh    = (short*)(smem + OFF_XH);
  short*          wh    = (short*)(smem + OFF_WH);
  unsigned short* u_l   = (unsigned short*)(smem + OFF_U);
  float*          si_l  = (float*)(smem + OFF_SI);
  float4*         pk4   = (float4*)(smem + OFF_PK4);
  float*          redb  = (float*)(smem + OFF_REDB);
  float*          rmax  = (float*)(smem + OFF_RMAX);
  float*          umaxl = (float*)(smem + OFF_UMAX);
  float*          xsql  = (float*)(smem + OFF_XSQL);
  float*          wsql  = (float*)(smem + OFF_WSQL);
  float*          kgaml = (float*)(smem + OFF_KGAM);
  float*          alphl = (float*)(smem + OFF_ALPH);

  const int t    = threadIdx.x;
  const int R0   = blockIdx.x * NR;
  const int wv   = t >> 6;
  const int wl   = t & 63;
  const int ml   = wl & 15;               // MFMA m/n lane
  const int qd   = wl >> 4;               // MFMA quad
  const int pcol = wv * 16 + ml;
  const int xrow = t >> 4, xq = t & 15;   // staging roles

  // ---- GEMM: D = x . w^T, BK=128, 4 chunks, register prefetch ----
  float xsq_acc = 0.f;
  float wacc[4] = {0.f, 0.f, 0.f, 0.f};
  floatx4 acc = {0.f, 0.f, 0.f, 0.f};
  float4 xr0, xr1, wr[4][2];

  {   // prefetch chunk 0
    const float* xp = &x[(size_t)(R0 + xrow) * NF + xq * 8];
    xr0 = *(const float4*)&xp[0];  xr1 = *(const float4*)&xp[4];
    #pragma unroll
    for (int g = 0; g < 4; ++g) {
      const int row = wv * 16 + g * 4 + (wl >> 4);
      const float* wp = &w[(size_t)row * NF + xq * 8];
      wr[g][0] = *(const float4*)&wp[0];  wr[g][1] = *(const float4*)&wp[4];
    }
  }
  for (int ch = 0; ch < 4; ++ch) {
    __syncthreads();                      // prev chunk's frags consumed
    {
      xsq_acc += xr0.x*xr0.x + xr0.y*xr0.y + xr0.z*xr0.z + xr0.w*xr0.w
               + xr1.x*xr1.x + xr1.y*xr1.y + xr1.z*xr1.z + xr1.w*xr1.w;
      *(uint2*)&xh[xrow * 136 + xq * 8]     = pkbf(xr0);
      *(uint2*)&xh[xrow * 136 + xq * 8 + 4] = pkbf(xr1);
    }
    #pragma unroll
    for (int g = 0; g < 4; ++g) {
      const int row = wv * 16 + g * 4 + (wl >> 4);
      float4 a = wr[g][0], b = wr[g][1];
      wacc[g] += a.x*a.x + a.y*a.y + a.z*a.z + a.w*a.w
               + b.x*b.x + b.y*b.y + b.z*b.z + b.w*b.w;
      *(uint2*)&wh[row * 136 + xq * 8]     = pkbf(a);
      *(uint2*)&wh[row * 136 + xq * 8 + 4] = pkbf(b);
    }
    __syncthreads();
    if (ch < 3) {                         // prefetch next chunk (overlaps MFMA)
      const int kb = (ch + 1) * 128;
      const float* xp = &x[(size_t)(R0 + xrow) * NF + kb + xq * 8];
      xr0 = *(const float4*)&xp[0];  xr1 = *(const float4*)&xp[4];
      #pragma unroll
      for (int g = 0; g < 4; ++g) {
        const int row = wv * 16 + g * 4 + (wl >> 4);
        const float* wp = &w[(size_t)row * NF + kb + xq * 8];
        wr[g][0] = *(const float4*)&wp[0];  wr[g][1] = *(const float4*)&wp[4];
      }
    }
    #pragma unroll
    for (int ks = 0; ks < 4; ++ks) {
      short8 a = *(const short8*)&xh[ml * 136 + ks * 32 + qd * 8];
      short8 b = *(const short8*)&wh[(wv * 16 + ml) * 136 + ks * 32 + qd * 8];
      acc = __builtin_amdgcn_mfma_f32_16x16x32_bf16(a, b, acc, 0, 0, 0);
    }
  }

  // ---- P1: beta partials; xsq/wsq butterflies; kgam/alpha ----
  const int p4 = t >> 2, q4 = t & 3;
  {
    const float* br = beta + p4 * NC + q4 * 25;
    float s = 0.f;
    #pragma unroll 5
    for (int j = 0; j < 25; ++j) { float b = br[j]; s = fmaf(b, b, s); }
    redb[q4 * 64 + p4] = s;
  }
  {
    float s = xsq_acc;
    s += __shfl_xor(s, 1, 64); s += __shfl_xor(s, 2, 64);
    s += __shfl_xor(s, 4, 64); s += __shfl_xor(s, 8, 64);
    if (xq == 0) xsql[xrow] = s;
  }
  #pragma unroll
  for (int g = 0; g < 4; ++g) {
    float s = wacc[g];
    s += __shfl_xor(s, 1, 64); s += __shfl_xor(s, 2, 64);
    s += __shfl_xor(s, 4, 64); s += __shfl_xor(s, 8, 64);
    if (xq == 0) wsql[wv * 16 + g * 4 + (wl >> 4)] = s;
  }
  if (t < 64) {
    float e = eta[t];
    kgaml[t] = -LOG2E * e * e;            // exp(-g*d) = exp2(kgam*d)
    alphl[t] = 1.f / (1.f + __expf(-xi[t]));
  }
  __syncthreads();                        // B1

  // ---- P2: si in MFMA-C layout + per-row 16-lane max partials ----
  float si4[4];
  {
    const float wq = wsql[pcol], kg = kgaml[pcol], al = alphl[pcol];
    #pragma unroll
    for (int i = 0; i < 4; ++i) {
      float d = xsql[qd * 4 + i] + wq - 2.f * acc[i];
      si4[i] = al * exp2f(kg * d);
    }
    #pragma unroll
    for (int i = 0; i < 4; ++i) {
      float m = si4[i];
      m = fmaxf(m, __shfl_xor(m, 1, 64)); m = fmaxf(m, __shfl_xor(m, 2, 64));
      m = fmaxf(m, __shfl_xor(m, 4, 64)); m = fmaxf(m, __shfl_xor(m, 8, 64));
      if (ml == 0) rmax[(qd * 4 + i) * 4 + wv] = m;
    }
  }
  __syncthreads();                        // B2

  // ---- P3: si finalize -> si_l; u fill (bf16, over dead staging) + umax ----
  #pragma unroll
  for (int i = 0; i < 4; ++i) {
    const int row = qd * 4 + i;
    float m = fmaxf(fmaxf(rmax[row * 4 + 0], rmax[row * 4 + 1]),
                    fmaxf(rmax[row * 4 + 2], rmax[row * 4 + 3]));
    si_l[row * 64 + pcol] = si4[i] * (1.f / (m + EPSF));
  }
  {
    const float bi = 1.f / (((redb[p4] + redb[64 + p4]) + redb[128 + p4]) + redb[192 + p4]);
    float um = 0.f;
    #pragma unroll
    for (int i2 = 0; i2 < 8; ++i2) {
      const int q = q4 + 4 * i2;          // col quad 0..31 (NC=100 = quads 0..24)
      float4 uv = make_float4(0.f, 0.f, 0.f, 0.f);
      if (q < 25) {
        const float* br = beta + p4 * NC + q * 4;
        uv.x = br[0]*br[0]*bi; uv.y = br[1]*br[1]*bi;
        uv.z = br[2]*br[2]*bi; uv.w = br[3]*br[3]*bi;
      }
      um = fmaxf(um, fmaxf(fmaxf(uv.x, uv.y), fmaxf(uv.z, uv.w)));
      *(uint2*)&u_l[p4 * 128 + q * 4] = pkbf(uv);
    }
    um = fmaxf(um, __shfl_xor(um, 1, 64));
    um = fmaxf(um, __shfl_xor(um, 2, 64));
    if (q4 == 0) umaxl[p4] = um;
  }
  __syncthreads();                        // B3 (last barrier)

  // ---- scan: one WAVE per 4 rows, all 4 rows interleaved (ILP) ----
  const int l31   = wl & 31;
  const int cbase = l31 * 4;              // this lane's 4 classes
  const int pbase = (wl >> 5) * 32;       // half A: p 0..31, half B: 32..63
  const bool isA  = (wl < 32);

  // preload u (bf16) for my half's 32 p values, 4 classes/lane: 64 VGPRs
  uint2 ureg[32];
  #pragma unroll
  for (int i = 0; i < 32; ++i)
    ureg[i] = *(const uint2*)&u_l[(pbase + i) * 128 + cbase];

  // factors for all 4 rows (lane = p), 4 interleaved Kogge-Stone chains
  const float um = umaxl[wl];
  float ST[4], OT[4], P3[4], omfr[4];
  #pragma unroll
  for (int r = 0; r < 4; ++r) {
    float sp = si_l[(wv * 4 + r) * 64 + wl];
    float om = 1.f - sp;
    float cn = 1.f / fmaf(sp, um, om);    // scale: max_c(vt) ~ 1 -> T <= 1
    ST[r] = sp * cn;  OT[r] = om * cn;
    P3[r] = 3.f * OT[r];
  }
  #pragma unroll
  for (int d2 = 1; d2 < 64; d2 <<= 1) {
    float up0 = __shfl_up(P3[0], d2, 64);
    float up1 = __shfl_up(P3[1], d2, 64);
    float up2 = __shfl_up(P3[2], d2, 64);
    float up3 = __shfl_up(P3[3], d2, 64);
    if (wl >= d2) { P3[0] *= up0; P3[1] *= up1; P3[2] *= up2; P3[3] *= up3; }
  }
  #pragma unroll
  for (int r = 0; r < 4; ++r) {
    float Wv = (wl == 0) ? 0.f : P3[r] * (1.f / 9.f); // 3^(k-1) prod_{j<=k} omt
    omfr[r]  = rlane(P3[r], 63) * (1.f / 3.f);        // 3^63 prod omt
    pk4[(wv * 4 + r) * 64 + wl] = make_float4(ST[r], OT[r], Wv, 0.f);
  }
  // wave-private pk4: ds_write -> ds_read ordered by lgkmcnt, no barrier

  float4 T[4], S[4];
  #pragma unroll
  for (int r = 0; r < 4; ++r) {
    T[r] = make_float4(1.f, 1.f, 1.f, 1.f);
    S[r] = make_float4(0.f, 0.f, 0.f, 0.f);
  }
  #pragma unroll
  for (int i = 31; i >= 0; --i) {         // descending within my segment
    uint2 ud = ureg[i];                   // u shared by all 4 rows
    float u0 = __uint_as_float(ud.x << 16);
    float u1 = __uint_as_float(ud.x & 0xffff0000u);
    float u2 = __uint_as_float(ud.y << 16);
    float u3 = __uint_as_float(ud.y & 0xffff0000u);
    #pragma unroll
    for (int r = 0; r < 4; ++r) {
      float4 f = pk4[(wv * 4 + r) * 64 + pbase + i]; // (st,ot,W) broadcast
      S[r].x = fmaf(f.z, T[r].x, S[r].x); S[r].y = fmaf(f.z, T[r].y, S[r].y);
      S[r].z = fmaf(f.z, T[r].z, S[r].z); S[r].w = fmaf(f.z, T[r].w, S[r].w);
      T[r].x *= fmaf(f.x, u0, f.y);
      T[r].y *= fmaf(f.x, u1, f.y);
      T[r].z *= fmaf(f.x, u2, f.y);
      T[r].w *= fmaf(f.x, u3, f.y);
    }
  }

  // combine halves: (T,S)_full = (T_A*T_B, S_A*T_B + S_B), 4 rows interleaved
  #pragma unroll
  for (int r = 0; r < 4; ++r) {
    float4 To, So;
    To.x = __shfl_xor(T[r].x, 32, 64); To.y = __shfl_xor(T[r].y, 32, 64);
    To.z = __shfl_xor(T[r].z, 32, 64); To.w = __shfl_xor(T[r].w, 32, 64);
    So.x = __shfl_xor(S[r].x, 32, 64); So.y = __shfl_xor(S[r].y, 32, 64);
    So.z = __shfl_xor(S[r].z, 32, 64); So.w = __shfl_xor(S[r].w, 32, 64);
    #define CMB(c) { \
      float SA = isA ? S[r].c : So.c; \
      float TB = isA ? To.c : T[r].c; \
      float SB = isA ? So.c : S[r].c; \
      S[r].c = fmaf(SA, TB, SB);  T[r].c = T[r].c * To.c; }
    CMB(x) CMB(y) CMB(z) CMB(w)
    #undef CMB
  }

  // finalize + normalize + store, 4 independent rows (scheduler interleaves)
  #pragma unroll
  for (int r = 0; r < 4; ++r) {
    const int srow = wv * 4 + r;
    float m0 = fmaf(2.f, S[r].x, T[r].x) - omfr[r];
    float m1 = fmaf(2.f, S[r].y, T[r].y) - omfr[r];
    float m2 = fmaf(2.f, S[r].z, T[r].z) - omfr[r];
    float m3 = fmaf(2.f, S[r].w, T[r].w) - omfr[r];
    if (l31 >= 25) { m0 = 0.f; m1 = 0.f; m2 = 0.f; m3 = 0.f; }
    float ss = (m0 + m1) + (m2 + m3);
    #pragma unroll
    for (int msk = 1; msk < 32; msk <<= 1) ss += __shfl_xor(ss, msk, 64);
    float rn = 1.f / (ss + omfr[r]);
    float* orow = &out[(size_t)(R0 + srow) * 101];
    if (wl < 25) {
      orow[wl * 4 + 0] = m0 * rn; orow[wl * 4 + 1] = m1 * rn;
      orow[wl * 4 + 2] = m2 * rn; orow[wl * 4 + 3] = m3 * rn;
    } else if (wl == 25) {
      orow[100] = omfr[r] * rn;
    }
  }
}

extern "C" void kernel_launch(void* const* d_in, const int* in_sizes, int n_in,
                              void* d_out, int out_size, void* d_ws, size_t ws_size,
                              hipStream_t stream)
{
  const float* x    = (const float*)d_in[0];
  const float* w    = (const float*)d_in[1];
  const float* xi   = (const float*)d_in[2];
  const float* eta  = (const float*)d_in[3];
  const float* beta = (const float*)d_in[4];
  (void)d_ws; (void)ws_size;
  hipLaunchKernelGGL(ds_one, dim3(NB / NR), dim3(256), 0, stream,
                     x, w, xi, eta, beta, (float*)d_out);
}